// Round 6
// baseline (8434.843 us; speedup 1.0000x reference)
//
#include <hip/hip_runtime.h>
#include <hip/hip_bf16.h>
#include <cstddef>

#define S_LEN 512
#define BATCH 64
#define HID 256
#define G3 768
#define SB (S_LEN*BATCH)
#define D2 512

typedef unsigned short u16;
typedef __attribute__((ext_vector_type(8))) short s16x8;
typedef __attribute__((ext_vector_type(8))) _Float16 f16x8;
typedef __attribute__((ext_vector_type(4))) float f32x4;

__device__ __forceinline__ float bf2f(u16 u) {
    return __uint_as_float(((unsigned)u) << 16);
}
__device__ __forceinline__ u16 f2bf(float f) {
    unsigned u = __float_as_uint(f);
    unsigned r = (u + 0x7FFFu + ((u >> 16) & 1u)) >> 16;
    return (u16)r;
}
__device__ __forceinline__ float fast_rcp(float x) {
#if __has_builtin(__builtin_amdgcn_rcpf)
    return __builtin_amdgcn_rcpf(x);
#else
    return 1.f / x;
#endif
}
__device__ __forceinline__ void gload_lds16(const void* g, void* l) {
    __builtin_amdgcn_global_load_lds((const __attribute__((address_space(1))) void*)g,
                                     (__attribute__((address_space(3))) void*)l, 16, 0, 0);
}
__device__ __forceinline__ void bar_lgkm() {
    asm volatile("s_waitcnt lgkmcnt(0)" ::: "memory");
    __builtin_amdgcn_s_barrier();
    __builtin_amdgcn_sched_barrier(0);
}
__device__ __forceinline__ void wait_vm0() {
    asm volatile("s_waitcnt vmcnt(0)" ::: "memory");
}

// ---------- prep kernels ----------
__global__ void f32_to_bf16(const float* __restrict__ in, u16* __restrict__ out, long n) {
    long i = (long)blockIdx.x * 256 + threadIdx.x;
    if (i < n) out[i] = f2bf(in[i]);
}
__global__ void f32_to_f16(const float* __restrict__ in, _Float16* __restrict__ out, long n) {
    long i = (long)blockIdx.x * 256 + threadIdx.x;
    if (i < n) out[i] = (_Float16)in[i];
}
// biasT[l][d][g] = b_ih(l)[d][g] + (g<512 ? b_hh[l][d][g] : 0)
// b_hh_n must stay INSIDE the r* product (reference: n = tanh(gi_n + r*(h@W_n + b_hh_n)))
__global__ void add_bias(const float* __restrict__ bih0, const float* __restrict__ bihl,
                         const float* __restrict__ bhh, float* __restrict__ outb) {
    int i = blockIdx.x * 256 + threadIdx.x;
    if (i >= 6 * 1536) return;
    int l = i / 1536, r = i - l * 1536;
    int g = r % 768;
    float bi = (l == 0) ? bih0[r] : bihl[(l - 1) * 1536 + r];
    outb[i] = bi + ((g < 512) ? bhh[i] : 0.f);
}

// ---------- input GEMM (MFMA): gi[d][m][g] = sum_k A[m][k]*W[d][g][k] + biasT[d][g] ----------
__global__ __launch_bounds__(256, 2) void gemm_mfma(
    const u16* __restrict__ A,
    const u16* __restrict__ Bt,
    const float* __restrict__ bias,   // [2][768]  (b_ih + r/z part of b_hh)
    u16* __restrict__ Cg,
    int K)
{
    int d = blockIdx.z;
    const u16* Bb = Bt + (size_t)d * 768 * K;
    const float* bi = bias + d * G3;
    u16* Cm = Cg + (size_t)d * SB * G3;

    int n0 = blockIdx.x * 128;
    int m0 = blockIdx.y * 128;
    int tid = threadIdx.x;
    int wave = tid >> 6, lane = tid & 63;
    int wm = wave >> 1, wn = wave & 1;

    __shared__ u16 Asm[128 * 32];
    __shared__ u16 Bsm[128 * 32];

    f32x4 acc[4][4] = {};

    for (int k0 = 0; k0 < K; k0 += 32) {
#pragma unroll
        for (int p = 0; p < 2; p++) {
            int c = p * 256 + wave * 64 + lane;
            int row = c >> 2, kc = c & 3;
            const u16* srcA = A + (size_t)(m0 + row) * K + k0 + kc * 8;
            const u16* srcB = Bb + (size_t)(n0 + row) * K + k0 + kc * 8;
            gload_lds16(srcA, &Asm[(p * 256 + wave * 64) * 8]);
            gload_lds16(srcB, &Bsm[(p * 256 + wave * 64) * 8]);
        }
        __syncthreads();

        s16x8 af[4], bfr[4];
#pragma unroll
        for (int i = 0; i < 4; i++) {
            int arow = wm * 64 + i * 16 + (lane & 15);
            af[i] = *reinterpret_cast<const s16x8*>(&Asm[arow * 32 + (lane >> 4) * 8]);
            int brow = wn * 64 + i * 16 + (lane & 15);
            bfr[i] = *reinterpret_cast<const s16x8*>(&Bsm[brow * 32 + (lane >> 4) * 8]);
        }
#pragma unroll
        for (int i = 0; i < 4; i++)
#pragma unroll
            for (int j = 0; j < 4; j++)
                acc[i][j] = __builtin_amdgcn_mfma_f32_16x16x32_bf16(af[i], bfr[j], acc[i][j], 0, 0, 0);
        __syncthreads();
    }

    int lcol = lane & 15, lrow4 = (lane >> 4) * 4;
#pragma unroll
    for (int i = 0; i < 4; i++) {
#pragma unroll
        for (int j = 0; j < 4; j++) {
            int n = n0 + wn * 64 + j * 16 + lcol;
            float bv = bi[n];
#pragma unroll
            for (int q = 0; q < 4; q++) {
                int m = m0 + wm * 64 + i * 16 + lrow4 + q;
                Cm[(size_t)m * G3 + n] = f2bf(acc[i][j][q] + bv);
            }
        }
    }
}

// ---------- MFMA recurrent scan ----------
// Block = 16 batch rows × 1 direction, 512 threads (8 waves).
// Per step: gh[16][768] = h[16][256] @ Whh^T via 48 MFMA/wave; wave w owns gate
// n-tiles {w,8+w,16+w,24+w,32+w,40+w} so r/z/n of its h-columns are in-register.
// Weights persistent in VGPRs (B-frags, 192 regs). h: f32 in regs + f16 LDS tiles.
__global__ __launch_bounds__(512, 2) void scan_mfma(
    const _Float16* __restrict__ whh16,  // [12][768][256] f16 (native layout, converted)
    const u16* __restrict__ gi,          // [2][SB][768] bf16 (b_ih + r/z b_hh folded)
    const float* __restrict__ bhh,       // [6][2][768] f32 (for the n-gate term)
    const float* __restrict__ h0,        // [12][64][256] f32
    u16* __restrict__ outc,              // [SB][512] bf16 or nullptr
    float* __restrict__ finals,          // [12][64][256] f32
    int layer)
{
    int b0 = blockIdx.x * 16;
    int d  = blockIdx.y;
    int ld = layer * 2 + d;
    int tid = threadIdx.x;
    int wv = tid >> 6, lane = tid & 63;
    int lr = lane & 15;      // frag row (A) / col (B,C)
    int lq = lane >> 4;      // quarter
    int r0 = lq * 4;         // C rows base

    __shared__ alignas(16) _Float16 h_tiles[8][16][32];   // 8 KB: [kt][row][k%32]
    __shared__ alignas(16) u16 gi_lds[2][16][G3];         // 48 KB double buffer

    const _Float16* Wl = whh16 + (size_t)ld * G3 * HID;
    const u16* gid = gi + (size_t)d * (size_t)SB * G3;

    // ---- persistent weight B-frags: lane holds W[g = nt*16+lr][kt*32 + lq*8 ..+8]
    f16x8 bfrag[6][8];
#pragma unroll
    for (int i = 0; i < 6; i++) {
        int nt = (i & 1) ? (8 + wv) + (i >> 1) * 16 : wv + (i >> 1) * 16;
        // i: 0->wv, 1->8+wv, 2->16+wv, 3->24+wv, 4->32+wv, 5->40+wv
        int g = nt * 16 + lr;
#pragma unroll
        for (int kt = 0; kt < 8; kt++)
            bfrag[i][kt] = *reinterpret_cast<const f16x8*>(Wl + (size_t)g * HID + kt * 32 + lq * 8);
    }

    // ---- h0 -> hreg (f32) + h_tiles (f16); b_hh_n per-lane registers
    int c0 = wv * 16 + lr;          // colgroup wv
    int c1 = (8 + wv) * 16 + lr;    // colgroup 8+wv
    float bhn0 = bhh[(size_t)ld * G3 + 2 * HID + c0];
    float bhn1 = bhh[(size_t)ld * G3 + 2 * HID + c1];
    float hreg0[4], hreg1[4];
#pragma unroll
    for (int q = 0; q < 4; q++) {
        float hv0 = h0[(size_t)ld * BATCH * HID + (b0 + r0 + q) * HID + c0];
        float hv1 = h0[(size_t)ld * BATCH * HID + (b0 + r0 + q) * HID + c1];
        hreg0[q] = hv0; hreg1[q] = hv1;
        h_tiles[c0 >> 5][r0 + q][c0 & 31] = (_Float16)hv0;
        h_tiles[c1 >> 5][r0 + q][c1 & 31] = (_Float16)hv1;
    }

    // ---- gi DMA: wave wv copies its 3 KB slice
    auto dma_gi = [&](int s, int buf) {
        const char* src = (const char*)(gid + ((size_t)s * BATCH + b0) * G3);
        char* dst = (char*)&gi_lds[buf][0][0];
#pragma unroll
        for (int i = 0; i < 3; i++) {
            int off = wv * 3072 + i * 1024;
            gload_lds16(src + off + lane * 16, dst + off);
        }
    };

    dma_gi(d ? (S_LEN - 1) : 0, 0);
    wait_vm0();
    __syncthreads();

    for (int t = 0; t < S_LEN; t++) {
        int s = d ? (S_LEN - 1 - t) : t;
        int buf = t & 1;
        if (t + 1 < S_LEN) dma_gi(d ? (s - 1) : (s + 1), buf ^ 1);

        // ---- gate matmul: 8 kt × 6 nt MFMA, zero-init acc
        f32x4 acc[6] = {};
#pragma unroll
        for (int kt = 0; kt < 8; kt++) {
            f16x8 a = *reinterpret_cast<const f16x8*>(&h_tiles[kt][lr][lq * 8]);
#pragma unroll
            for (int i = 0; i < 6; i++)
                acc[i] = __builtin_amdgcn_mfma_f32_16x16x32_f16(a, bfrag[i][kt], acc[i], 0, 0, 0);
        }
        bar_lgkm();   // all A-frag reads done -> safe to overwrite h_tiles

        // ---- in-register GRU update; lane owns (rows r0..r0+3) x (cols c0, c1)
        const u16* gb = &gi_lds[buf][0][0];
#pragma unroll
        for (int q = 0; q < 4; q++) {
            int row = r0 + q;
            const u16* gr = gb + row * G3;
            // colgroup 0: R=acc[0], Z=acc[2], N=acc[4]
            {
                float gir = bf2f(gr[c0]);
                float giz = bf2f(gr[HID + c0]);
                float gin = bf2f(gr[2 * HID + c0]);
                float r = fast_rcp(1.f + __expf(-(gir + acc[0][q])));
                float z = fast_rcp(1.f + __expf(-(giz + acc[2][q])));
                float xn = gin + r * (acc[4][q] + bhn0);
                float e2 = __expf(2.f * xn);
                float n = 1.f - 2.f * fast_rcp(e2 + 1.f);
                float hn = (1.f - z) * n + z * hreg0[q];
                hreg0[q] = hn;
                h_tiles[c0 >> 5][row][c0 & 31] = (_Float16)hn;
                if (outc) outc[((size_t)s * BATCH + b0 + row) * D2 + d * HID + c0] = f2bf(hn);
            }
            // colgroup 1: R=acc[1], Z=acc[3], N=acc[5]
            {
                float gir = bf2f(gr[c1]);
                float giz = bf2f(gr[HID + c1]);
                float gin = bf2f(gr[2 * HID + c1]);
                float r = fast_rcp(1.f + __expf(-(gir + acc[1][q])));
                float z = fast_rcp(1.f + __expf(-(giz + acc[3][q])));
                float xn = gin + r * (acc[5][q] + bhn1);
                float e2 = __expf(2.f * xn);
                float n = 1.f - 2.f * fast_rcp(e2 + 1.f);
                float hn = (1.f - z) * n + z * hreg1[q];
                hreg1[q] = hn;
                h_tiles[c1 >> 5][row][c1 & 31] = (_Float16)hn;
                if (outc) outc[((size_t)s * BATCH + b0 + row) * D2 + d * HID + c1] = f2bf(hn);
            }
        }
        wait_vm0();   // next step's gi DMA landed (also drains outc stores)
        bar_lgkm();   // h_tiles writes visible to all waves
    }

#pragma unroll
    for (int q = 0; q < 4; q++) {
        finals[(size_t)ld * BATCH * HID + (b0 + r0 + q) * HID + c0] = hreg0[q];
        finals[(size_t)ld * BATCH * HID + (b0 + r0 + q) * HID + c1] = hreg1[q];
    }
}

extern "C" void kernel_launch(void* const* d_in, const int* in_sizes, int n_in,
                              void* d_out, int out_size, void* d_ws, size_t ws_size,
                              hipStream_t stream) {
    const float* x     = (const float*)d_in[0];
    const float* h0    = (const float*)d_in[1];
    const float* w_ih0 = (const float*)d_in[2];
    const float* b_ih0 = (const float*)d_in[3];
    const float* w_ih  = (const float*)d_in[4];
    const float* b_ih  = (const float*)d_in[5];
    const float* w_hh  = (const float*)d_in[6];
    const float* b_hh  = (const float*)d_in[7];
    float* out = (float*)d_out;

    char* ws = (char*)d_ws;
    // whh16 f16 [12][768][256]  @ 0           4,718,592
    // wbf0  bf16 [2][768][128]  @ 4,718,592     393,216
    // wbfl  bf16 [5][2][768][512] @ 5,111,808 7,864,320
    // biasT f32 [6][2][768]     @ 12,976,128     36,864
    // gi    bf16 [2][SB][768]   @ 13,012,992 100,663,296
    // curA  bf16 [SB][512]      @ 113,676,288 33,554,432
    // curB  bf16 [SB][512]      @ 147,230,720 33,554,432
    _Float16* whh16 = (_Float16*)(ws + 0);
    u16* wbf0  = (u16*)(ws + 4718592);
    u16* wbfl  = (u16*)(ws + 5111808);
    float* biasT = (float*)(ws + 12976128);
    u16* gi    = (u16*)(ws + 13012992);
    u16* curA  = (u16*)(ws + 113676288);
    u16* curB  = (u16*)(ws + 147230720);

    f32_to_f16<<<(2359296 + 255) / 256, 256, 0, stream>>>(w_hh, whh16, 2359296L);
    f32_to_bf16<<<(196608 + 255) / 256, 256, 0, stream>>>(w_ih0, wbf0, 196608L);
    f32_to_bf16<<<(3932160 + 255) / 256, 256, 0, stream>>>(w_ih, wbfl, 3932160L);
    f32_to_bf16<<<(4194304 + 255) / 256, 256, 0, stream>>>(x, curA, 4194304L);
    add_bias<<<(9216 + 255) / 256, 256, 0, stream>>>(b_ih0, b_ih, b_hh, biasT);

    u16* cin = curA;
    u16* cout_ = curB;
    for (int l = 0; l < 6; l++) {
        int K = l ? 512 : 128;
        const u16* wt = l ? (wbfl + (size_t)(l - 1) * 2 * 768 * 512) : wbf0;
        const float* bi = biasT + (size_t)l * 1536;
        dim3 g(6, 256, 2);
        gemm_mfma<<<g, 256, 0, stream>>>(cin, wt, bi, gi, K);
        scan_mfma<<<dim3(4, 2), 512, 0, stream>>>(whh16, gi, b_hh, h0,
                                                  (l < 5) ? cout_ : (u16*)nullptr, out, l);
        u16* tmp = cin; cin = cout_; cout_ = tmp;
    }
}

// Round 7
// 7498.749 us; speedup vs baseline: 1.1248x; 1.1248x over previous
//
#include <hip/hip_runtime.h>
#include <hip/hip_bf16.h>
#include <cstddef>

#define S_LEN 512
#define BATCH 64
#define HID 256
#define G3 768
#define SB (S_LEN*BATCH)
#define D2 512

typedef unsigned short u16;
typedef __attribute__((ext_vector_type(8))) short s16x8;
typedef __attribute__((ext_vector_type(8))) _Float16 f16x8;
typedef __attribute__((ext_vector_type(4))) float f32x4;

__device__ __forceinline__ float bf2f(u16 u) {
    return __uint_as_float(((unsigned)u) << 16);
}
__device__ __forceinline__ u16 f2bf(float f) {
    unsigned u = __float_as_uint(f);
    unsigned r = (u + 0x7FFFu + ((u >> 16) & 1u)) >> 16;
    return (u16)r;
}
__device__ __forceinline__ float fast_rcp(float x) {
#if __has_builtin(__builtin_amdgcn_rcpf)
    return __builtin_amdgcn_rcpf(x);
#else
    return 1.f / x;
#endif
}
__device__ __forceinline__ void gload_lds16(const void* g, void* l) {
    __builtin_amdgcn_global_load_lds((const __attribute__((address_space(1))) void*)g,
                                     (__attribute__((address_space(3))) void*)l, 16, 0, 0);
}

// ---------- prep kernels ----------
__global__ void f32_to_bf16(const float* __restrict__ in, u16* __restrict__ out, long n) {
    long i = (long)blockIdx.x * 256 + threadIdx.x;
    if (i < n) out[i] = f2bf(in[i]);
}
__global__ void f32_to_f16(const float* __restrict__ in, _Float16* __restrict__ out, long n) {
    long i = (long)blockIdx.x * 256 + threadIdx.x;
    if (i < n) out[i] = (_Float16)in[i];
}
// biasT[l][d][g] = b_ih(l)[d][g] + (g<512 ? b_hh[l][d][g] : 0)
// b_hh_n stays INSIDE the r* product (n = tanh(gi_n + r*(h@W_n + b_hh_n)))
__global__ void add_bias(const float* __restrict__ bih0, const float* __restrict__ bihl,
                         const float* __restrict__ bhh, float* __restrict__ outb) {
    int i = blockIdx.x * 256 + threadIdx.x;
    if (i >= 6 * 1536) return;
    int l = i / 1536, r = i - l * 1536;
    int g = r % 768;
    float bi = (l == 0) ? bih0[r] : bihl[(l - 1) * 1536 + r];
    outb[i] = bi + ((g < 512) ? bhh[i] : 0.f);
}

// ---------- input GEMM (MFMA) ----------
__global__ __launch_bounds__(256, 2) void gemm_mfma(
    const u16* __restrict__ A,
    const u16* __restrict__ Bt,
    const float* __restrict__ bias,
    u16* __restrict__ Cg,
    int K)
{
    int d = blockIdx.z;
    const u16* Bb = Bt + (size_t)d * 768 * K;
    const float* bi = bias + d * G3;
    u16* Cm = Cg + (size_t)d * SB * G3;

    int n0 = blockIdx.x * 128;
    int m0 = blockIdx.y * 128;
    int tid = threadIdx.x;
    int wave = tid >> 6, lane = tid & 63;
    int wm = wave >> 1, wn = wave & 1;

    __shared__ u16 Asm[128 * 32];
    __shared__ u16 Bsm[128 * 32];

    f32x4 acc[4][4] = {};

    for (int k0 = 0; k0 < K; k0 += 32) {
#pragma unroll
        for (int p = 0; p < 2; p++) {
            int c = p * 256 + wave * 64 + lane;
            int row = c >> 2, kc = c & 3;
            const u16* srcA = A + (size_t)(m0 + row) * K + k0 + kc * 8;
            const u16* srcB = Bb + (size_t)(n0 + row) * K + k0 + kc * 8;
            gload_lds16(srcA, &Asm[(p * 256 + wave * 64) * 8]);
            gload_lds16(srcB, &Bsm[(p * 256 + wave * 64) * 8]);
        }
        __syncthreads();

        s16x8 af[4], bfr[4];
#pragma unroll
        for (int i = 0; i < 4; i++) {
            int arow = wm * 64 + i * 16 + (lane & 15);
            af[i] = *reinterpret_cast<const s16x8*>(&Asm[arow * 32 + (lane >> 4) * 8]);
            int brow = wn * 64 + i * 16 + (lane & 15);
            bfr[i] = *reinterpret_cast<const s16x8*>(&Bsm[brow * 32 + (lane >> 4) * 8]);
        }
#pragma unroll
        for (int i = 0; i < 4; i++)
#pragma unroll
            for (int j = 0; j < 4; j++)
                acc[i][j] = __builtin_amdgcn_mfma_f32_16x16x32_bf16(af[i], bfr[j], acc[i][j], 0, 0, 0);
        __syncthreads();
    }

    int lcol = lane & 15, lrow4 = (lane >> 4) * 4;
#pragma unroll
    for (int i = 0; i < 4; i++) {
#pragma unroll
        for (int j = 0; j < 4; j++) {
            int n = n0 + wn * 64 + j * 16 + lcol;
            float bv = bi[n];
#pragma unroll
            for (int q = 0; q < 4; q++) {
                int m = m0 + wm * 64 + i * 16 + lrow4 + q;
                Cm[(size_t)m * G3 + n] = f2bf(acc[i][j][q] + bv);
            }
        }
    }
}

// ---------- MFMA recurrent scan (v2: 1 barrier/step, counted vmcnt, linear h tiles) ----------
__global__ __launch_bounds__(512, 2) void scan_mfma(
    const _Float16* __restrict__ whh16,  // [12][768][256] f16
    const u16* __restrict__ gi,          // [2][SB][768] bf16 (b_ih + r/z b_hh folded)
    const float* __restrict__ bhh,       // [6][2][768] f32 (n-gate term)
    const float* __restrict__ h0,        // [12][64][256] f32
    u16* __restrict__ outc,              // [SB][512] bf16 or nullptr
    float* __restrict__ finals,          // [12][64][256] f32
    int layer)
{
    int b0 = blockIdx.x * 16;
    int d  = blockIdx.y;
    int ld = layer * 2 + d;
    int tid = threadIdx.x;
    int wv = tid >> 6, lane = tid & 63;
    int lr = lane & 15;      // frag row (A) / col (B,C)
    int lq = lane >> 4;      // quarter
    int r0 = lq * 4;         // C rows base

    // h double-buffer, linear per-quarter layout: [p][kt][lq][row][sub]
    // A-frag read = lane-sequential 16B chunks (conflict-free).
    __shared__ alignas(16) _Float16 h_tiles[2][8][4][16][8];  // 16 KB
    __shared__ alignas(16) u16 gi_lds[2][16][G3];             // 48 KB

    const _Float16* Wl = whh16 + (size_t)ld * G3 * HID;
    const u16* gid = gi + (size_t)d * (size_t)SB * G3;

    // ---- persistent weight B-frags: lane holds W[g = nt*16+lr][kt*32 + lq*8 ..+8]
    f16x8 bfrag[6][8];
#pragma unroll
    for (int i = 0; i < 6; i++) {
        int nt = (i & 1) ? (8 + wv) + (i >> 1) * 16 : wv + (i >> 1) * 16;
        int g = nt * 16 + lr;
#pragma unroll
        for (int kt = 0; kt < 8; kt++)
            bfrag[i][kt] = *reinterpret_cast<const f16x8*>(Wl + (size_t)g * HID + kt * 32 + lq * 8);
    }

    int c0 = wv * 16 + lr;          // colgroup wv      (nt i=0,2,4)
    int c1 = (8 + wv) * 16 + lr;    // colgroup 8+wv    (nt i=1,3,5)
    float bhn0 = bhh[(size_t)ld * G3 + 2 * HID + c0];
    float bhn1 = bhh[(size_t)ld * G3 + 2 * HID + c1];
    float hreg0[4], hreg1[4];
#pragma unroll
    for (int q = 0; q < 4; q++) {
        float hv0 = h0[(size_t)ld * BATCH * HID + (b0 + r0 + q) * HID + c0];
        float hv1 = h0[(size_t)ld * BATCH * HID + (b0 + r0 + q) * HID + c1];
        hreg0[q] = hv0; hreg1[q] = hv1;
        h_tiles[0][c0 >> 5][(c0 >> 3) & 3][r0 + q][c0 & 7] = (_Float16)hv0;
        h_tiles[0][c1 >> 5][(c1 >> 3) & 3][r0 + q][c1 & 7] = (_Float16)hv1;
    }

    // ---- gi DMA: 3 gload_lds x 16B per wave = 24 KB/block-step
    auto dma_gi = [&](int s, int buf) {
        const char* src = (const char*)(gid + ((size_t)s * BATCH + b0) * G3);
        char* dst = (char*)&gi_lds[buf][0][0];
#pragma unroll
        for (int i = 0; i < 3; i++) {
            int off = wv * 3072 + i * 1024;
            gload_lds16(src + off + lane * 16, dst + off);
        }
    };

    dma_gi(d ? (S_LEN - 1) : 0, 0);
    asm volatile("s_waitcnt vmcnt(0)" ::: "memory");
    __syncthreads();

    for (int t = 0; t < S_LEN; t++) {
        int s = d ? (S_LEN - 1 - t) : t;
        int buf = t & 1;   // gi buffer this step; also h read-buffer p
        if (t + 1 < S_LEN) dma_gi(d ? (s - 1) : (s + 1), buf ^ 1);

        // ---- gate matmul: read h_tiles[buf], 8 kt x 6 nt MFMA
        f32x4 acc[6] = {};
#pragma unroll
        for (int kt = 0; kt < 8; kt++) {
            f16x8 a = *reinterpret_cast<const f16x8*>(&h_tiles[buf][kt][lq][lr][0]);
#pragma unroll
            for (int i = 0; i < 6; i++)
                acc[i] = __builtin_amdgcn_mfma_f32_16x16x32_f16(a, bfrag[i][kt], acc[i], 0, 0, 0);
        }

        // ---- in-register GRU update; write h into h_tiles[buf^1]
        const u16* gb = &gi_lds[buf][0][0];
#pragma unroll
        for (int q = 0; q < 4; q++) {
            int row = r0 + q;
            const u16* gr = gb + row * G3;
            {
                float gir = bf2f(gr[c0]);
                float giz = bf2f(gr[HID + c0]);
                float gin = bf2f(gr[2 * HID + c0]);
                float r = fast_rcp(1.f + __expf(-(gir + acc[0][q])));
                float z = fast_rcp(1.f + __expf(-(giz + acc[2][q])));
                float xn = gin + r * (acc[4][q] + bhn0);
                float e2 = __expf(2.f * xn);
                float n = 1.f - 2.f * fast_rcp(e2 + 1.f);
                float hn = (1.f - z) * n + z * hreg0[q];
                hreg0[q] = hn;
                h_tiles[buf ^ 1][c0 >> 5][(c0 >> 3) & 3][row][c0 & 7] = (_Float16)hn;
                if (outc) outc[((size_t)s * BATCH + b0 + row) * D2 + d * HID + c0] = f2bf(hn);
            }
            {
                float gir = bf2f(gr[c1]);
                float giz = bf2f(gr[HID + c1]);
                float gin = bf2f(gr[2 * HID + c1]);
                float r = fast_rcp(1.f + __expf(-(gir + acc[1][q])));
                float z = fast_rcp(1.f + __expf(-(giz + acc[3][q])));
                float xn = gin + r * (acc[5][q] + bhn1);
                float e2 = __expf(2.f * xn);
                float n = 1.f - 2.f * fast_rcp(e2 + 1.f);
                float hn = (1.f - z) * n + z * hreg1[q];
                hreg1[q] = hn;
                h_tiles[buf ^ 1][c1 >> 5][(c1 >> 3) & 3][row][c1 & 7] = (_Float16)hn;
                if (outc) outc[((size_t)s * BATCH + b0 + row) * D2 + d * HID + c1] = f2bf(hn);
            }
        }
        // counted wait: drains the 3 gi-DMAs (oldest), NOT this step's 8 outc stores;
        // lgkmcnt(0) covers the h_tiles ds_writes. One barrier per step.
        asm volatile("s_waitcnt vmcnt(8) lgkmcnt(0)" ::: "memory");
        __builtin_amdgcn_s_barrier();
        __builtin_amdgcn_sched_barrier(0);
    }

#pragma unroll
    for (int q = 0; q < 4; q++) {
        finals[(size_t)ld * BATCH * HID + (b0 + r0 + q) * HID + c0] = hreg0[q];
        finals[(size_t)ld * BATCH * HID + (b0 + r0 + q) * HID + c1] = hreg1[q];
    }
}

extern "C" void kernel_launch(void* const* d_in, const int* in_sizes, int n_in,
                              void* d_out, int out_size, void* d_ws, size_t ws_size,
                              hipStream_t stream) {
    const float* x     = (const float*)d_in[0];
    const float* h0    = (const float*)d_in[1];
    const float* w_ih0 = (const float*)d_in[2];
    const float* b_ih0 = (const float*)d_in[3];
    const float* w_ih  = (const float*)d_in[4];
    const float* b_ih  = (const float*)d_in[5];
    const float* w_hh  = (const float*)d_in[6];
    const float* b_hh  = (const float*)d_in[7];
    float* out = (float*)d_out;

    char* ws = (char*)d_ws;
    _Float16* whh16 = (_Float16*)(ws + 0);
    u16* wbf0  = (u16*)(ws + 4718592);
    u16* wbfl  = (u16*)(ws + 5111808);
    float* biasT = (float*)(ws + 12976128);
    u16* gi    = (u16*)(ws + 13012992);
    u16* curA  = (u16*)(ws + 113676288);
    u16* curB  = (u16*)(ws + 147230720);

    f32_to_f16<<<(2359296 + 255) / 256, 256, 0, stream>>>(w_hh, whh16, 2359296L);
    f32_to_bf16<<<(196608 + 255) / 256, 256, 0, stream>>>(w_ih0, wbf0, 196608L);
    f32_to_bf16<<<(3932160 + 255) / 256, 256, 0, stream>>>(w_ih, wbfl, 3932160L);
    f32_to_bf16<<<(4194304 + 255) / 256, 256, 0, stream>>>(x, curA, 4194304L);
    add_bias<<<(9216 + 255) / 256, 256, 0, stream>>>(b_ih0, b_ih, b_hh, biasT);

    u16* cin = curA;
    u16* cout_ = curB;
    for (int l = 0; l < 6; l++) {
        int K = l ? 512 : 128;
        const u16* wt = l ? (wbfl + (size_t)(l - 1) * 2 * 768 * 512) : wbf0;
        const float* bi = biasT + (size_t)l * 1536;
        dim3 g(6, 256, 2);
        gemm_mfma<<<g, 256, 0, stream>>>(cin, wt, bi, gi, K);
        scan_mfma<<<dim3(4, 2), 512, 0, stream>>>(whh16, gi, b_hh, h0,
                                                  (l < 5) ? cout_ : (u16*)nullptr, out, l);
        u16* tmp = cin; cin = cout_; cout_ = tmp;
    }
}